// Round 5
// baseline (447.064 us; speedup 1.0000x reference)
//
#include <hip/hip_runtime.h>

#define BS 2048
#define EMB 1024
#define NHEAD 8
#define HDIM 128

typedef unsigned short u16;
typedef __attribute__((ext_vector_type(8))) short bf16x8;
typedef __attribute__((ext_vector_type(4))) float f32x4;

__device__ __forceinline__ u16 f32_bf16(float f) {
  unsigned u = __float_as_uint(f);
  u += 0x7fffu + ((u >> 16) & 1u);
  return (u16)(u >> 16);
}
__device__ __forceinline__ float bf2f(u16 x) {
  return __uint_as_float((unsigned)x << 16);
}

__device__ __forceinline__ void gld_lds16(const void* g, void* l) {
  __builtin_amdgcn_global_load_lds(
      (const __attribute__((address_space(1))) void*)g,
      (__attribute__((address_space(3))) void*)l, 16, 0, 0);
}

// ---------------- fp32 -> bf16: ALL weights/activations in ONE kernel ----------
// segs of 256K v4 (1M elems): [0,2)=x1 [2,4)=x2 [4]=Wq [5]=Wk [6]=Wv [7]=Wo
// [8,12)=W1 [12,16)=W2
struct CvtArgs { const float* src[8]; };
__global__ __launch_bounds__(256) void cvt_all(CvtArgs a, u16* __restrict__ dst) {
  long i = (long)blockIdx.x * 256 + threadIdx.x;  // v4 index
  int seg = (int)(i >> 18);
  const float* src; long b;
  if (seg < 2)       { src = a.src[0]; b = 0; }
  else if (seg < 4)  { src = a.src[1]; b = 2L << 18; }
  else if (seg == 4) { src = a.src[2]; b = 4L << 18; }
  else if (seg == 5) { src = a.src[3]; b = 5L << 18; }
  else if (seg == 6) { src = a.src[4]; b = 6L << 18; }
  else if (seg == 7) { src = a.src[5]; b = 7L << 18; }
  else if (seg < 12) { src = a.src[6]; b = 8L << 18; }
  else               { src = a.src[7]; b = 12L << 18; }
  float4 v = ((const float4*)src)[i - b];
  ushort4 o;
  o.x = f32_bf16(v.x); o.y = f32_bf16(v.y); o.z = f32_bf16(v.z); o.w = f32_bf16(v.w);
  ((ushort4*)dst)[i] = o;
}

// ---------------- GEMM core: C = A @ B^T (+bias), 128x128 tile, BK=32 ----------
// mode: 0 = fp32 out, 1 = bf16 out, 2 = bf16 transposed store (Ct[n][m])
__device__ __forceinline__ void gemm_core(
    const u16* __restrict__ A, const u16* __restrict__ B, void* __restrict__ Cp,
    const float* __restrict__ bias, int K, int lda, int ldb, int ldc,
    long cbase, int mode, int relu, int m0, int n0) {
  __shared__ __align__(16) u16 As[128 * 32];
  __shared__ __align__(16) u16 Bs[128 * 32];
  const int t = threadIdx.x;
  const int lane = t & 63, l15 = lane & 15, quad = lane >> 4;
  const int wv = t >> 6, wr = wv & 1, wc = wv >> 1;
  const int wbase = t & ~63;

  f32x4 acc[4][4];
#pragma unroll
  for (int r = 0; r < 4; ++r)
#pragma unroll
    for (int c = 0; c < 4; ++c) acc[r][c] = (f32x4){0.f, 0.f, 0.f, 0.f};

  for (int k0 = 0; k0 < K; k0 += 32) {
#pragma unroll
    for (int i = 0; i < 2; ++i) {
      int s = i * 256 + t;
      gld_lds16(A + (long)(m0 + (s >> 2)) * lda + k0 + (s & 3) * 8,
                As + (i * 256 + wbase) * 8);
    }
#pragma unroll
    for (int i = 0; i < 2; ++i) {
      int s = i * 256 + t;
      gld_lds16(B + (long)(n0 + (s >> 2)) * ldb + k0 + (s & 3) * 8,
                Bs + (i * 256 + wbase) * 8);
    }
    __syncthreads();
    bf16x8 fa[4], fb[4];
#pragma unroll
    for (int r = 0; r < 4; ++r)
      fa[r] = *(const bf16x8*)&As[(wr * 64 + r * 16 + l15) * 32 + quad * 8];
#pragma unroll
    for (int c = 0; c < 4; ++c)
      fb[c] = *(const bf16x8*)&Bs[(wc * 64 + c * 16 + l15) * 32 + quad * 8];
#pragma unroll
    for (int r = 0; r < 4; ++r)
#pragma unroll
      for (int c = 0; c < 4; ++c)
        acc[r][c] = __builtin_amdgcn_mfma_f32_16x16x32_bf16(fa[r], fb[c], acc[r][c], 0, 0, 0);
    __syncthreads();
  }

#pragma unroll
  for (int r = 0; r < 4; ++r)
#pragma unroll
    for (int c = 0; c < 4; ++c) {
      const int m = m0 + wr * 64 + r * 16 + quad * 4;
      const int n = n0 + wc * 64 + c * 16 + l15;
      const float bv = bias ? bias[n] : 0.f;
      f32x4 v = acc[r][c];
      if (mode == 2) {
        ushort4 o;
        o.x = f32_bf16(v[0] + bv);
        o.y = f32_bf16(v[1] + bv);
        o.z = f32_bf16(v[2] + bv);
        o.w = f32_bf16(v[3] + bv);
        *(ushort4*)((u16*)Cp + cbase + (long)n * ldc + m) = o;
      } else {
#pragma unroll
        for (int i = 0; i < 4; ++i) {
          float x = v[i] + bv;
          if (relu) x = fmaxf(x, 0.f);
          if (mode == 0)
            ((float*)Cp)[cbase + (long)(m + i) * ldc + n] = x;
          else
            ((u16*)Cp)[cbase + (long)(m + i) * ldc + n] = f32_bf16(x);
        }
      }
    }
}

// generic z-batched GEMM (linear z offsets in elements)
__global__ __launch_bounds__(256) void gemm_bt_k(
    const u16* __restrict__ A, const u16* __restrict__ B, void* __restrict__ C,
    const float* __restrict__ bias, int K, int lda, int ldb, int ldc,
    long aOffZ, long bOffZ, long cOffZ, int mode, int relu) {
  gemm_core(A + (long)blockIdx.z * aOffZ, B + (long)blockIdx.z * bOffZ, C, bias,
            K, lda, ldb, ldc, (long)blockIdx.z * cOffZ, mode, relu,
            blockIdx.y * 128, blockIdx.x * 128);
}

// Q/K/V projections in one launch: z=0 Q(x1), z=1 K(x2), z=2 V(x2, transposed out)
__global__ __launch_bounds__(256) void qkv_kernel(
    const u16* __restrict__ x1b, const u16* __restrict__ x2b,
    const u16* __restrict__ Wqb, const u16* __restrict__ Wkb, const u16* __restrict__ Wvb,
    const float* __restrict__ bq, const float* __restrict__ bk, const float* __restrict__ bv,
    u16* __restrict__ Qb, u16* __restrict__ Kb, u16* __restrict__ Vt) {
  const int z = blockIdx.z;
  const u16* A = (z == 0) ? x1b : x2b;
  const u16* B = (z == 0) ? Wqb : (z == 1) ? Wkb : Wvb;
  void* C = (z == 0) ? (void*)Qb : (z == 1) ? (void*)Kb : (void*)Vt;
  const float* bias = (z == 0) ? bq : (z == 1) ? bk : bv;
  const int mode = (z == 2) ? 2 : 1;
  const int ldc = (z == 2) ? 2048 : 1024;
  gemm_core(A, B, C, bias, 1024, 1024, 1024, ldc, 0, mode, 0,
            blockIdx.y * 128, blockIdx.x * 128);
}

// ---------------- fused attention: QK^T + softmax(heads) + PV -----------------
// grid: x = n-block (128 of 16 rows), y = m-split (4 of 512). 512 threads,
// 8 waves, LDS 32 KB, combined VGPR+AGPR budget <=128 -> 2 blocks/CU (TLP:
// co-resident block computes while the other drains at its barrier).
// Per m-tile of 128 (4 per block):
//   scores: direct-global BATCHED loads (kf[4]+qf[4] per head, issued before
//           the 4 dependent MFMAs), no staging, no barriers in the h-loop.
//           Wave w owns m-chunk w; acc holds all 8 heads -> per-lane softmax.
//   P -> LDS [h][16n][128m] bf16, XOR-swizzled (byte ^= (n&7)<<4). 32 KB.
//   PV: wave w owns head w; V direct-global batched vf[8] per mq.
// Only 2 barriers per m-tile (8/block). Partials reduced by reduce4p_bf16.
__global__ __launch_bounds__(512, 4) void attn_fused(
    const u16* __restrict__ Q, const u16* __restrict__ Km, const u16* __restrict__ Vt,
    u16* __restrict__ p0, u16* __restrict__ p1, u16* __restrict__ p2, u16* __restrict__ p3) {
  __shared__ __align__(16) u16 Ps[8 * 16 * 128];  // 32 KB, [h][n][m] swizzled
  const int t = threadIdx.x;
  const int lane = t & 63, l15 = lane & 15, quad = lane >> 4;
  const int w = t >> 6;
  const int n0 = blockIdx.x * 16;
  const int mz = blockIdx.y * 512;
  u16* part = (blockIdx.y == 0) ? p0 : (blockIdx.y == 1) ? p1 : (blockIdx.y == 2) ? p2 : p3;

  f32x4 accp[8];
#pragma unroll
  for (int c = 0; c < 8; ++c) accp[c] = (f32x4){0.f, 0.f, 0.f, 0.f};

  const u16* qrow = Q + (long)(n0 + l15) * 1024 + quad * 8;

  for (int it = 0; it < 4; ++it) {
    const int mb = mz + it * 128;
    f32x4 accs[8];
#pragma unroll
    for (int h = 0; h < 8; ++h) accs[h] = (f32x4){0.f, 0.f, 0.f, 0.f};

    const u16* krow = Km + (long)(mb + w * 16 + l15) * 1024 + quad * 8;
#pragma unroll
    for (int h = 0; h < 8; ++h) {
      // batch the 8 independent loads for this head, then 4 MFMAs
      bf16x8 kf[4], qf[4];
#pragma unroll
      for (int kk = 0; kk < 4; ++kk) {
        kf[kk] = *(const bf16x8*)&krow[h * 128 + kk * 32];
        qf[kk] = *(const bf16x8*)&qrow[h * 128 + kk * 32];
      }
#pragma unroll
      for (int kk = 0; kk < 4; ++kk)
        accs[h] = __builtin_amdgcn_mfma_f32_16x16x32_bf16(kf[kk], qf[kk], accs[h], 0, 0, 0);
    }

    // ---- softmax over heads, per-lane; i indexes m (rows of S^T) ----
    const float scale = 0.08838834764831845f;  // 1/sqrt(128)
#pragma unroll
    for (int i = 0; i < 4; ++i) {
      float mx = accs[0][i];
#pragma unroll
      for (int h = 1; h < 8; ++h) mx = fmaxf(mx, accs[h][i]);
      float sum = 0.f;
#pragma unroll
      for (int h = 0; h < 8; ++h) {
        float e = __expf((accs[h][i] - mx) * scale);
        accs[h][i] = e;
        sum += e;
      }
      float inv = 1.f / sum;
#pragma unroll
      for (int h = 0; h < 8; ++h) accs[h][i] *= inv;
    }

    __syncthreads();  // previous it's PV reads of Ps all done
    // ---- P -> LDS, m-packed ushort4, swizzled; n = l15 ----
#pragma unroll
    for (int h = 0; h < 8; ++h) {
      ushort4 o;
      o.x = f32_bf16(accs[h][0]);
      o.y = f32_bf16(accs[h][1]);
      o.z = f32_bf16(accs[h][2]);
      o.w = f32_bf16(accs[h][3]);
      *(ushort4*)((char*)Ps + h * 4096 + l15 * 256 +
                  ((w * 32 + quad * 8) ^ ((l15 & 7) << 4))) = o;
    }
    __syncthreads();  // Ps ready
    // ---- PV: head w; C[n16][d128] += P[n][m128] * Vt[d][m128]^T ----
#pragma unroll
    for (int mq = 0; mq < 4; ++mq) {
      bf16x8 vf[8];
#pragma unroll
      for (int c = 0; c < 8; ++c)
        vf[c] = *(const bf16x8*)&Vt[(long)(w * 128 + c * 16 + l15) * 2048 +
                                    mb + mq * 32 + quad * 8];
      bf16x8 pa = *(const bf16x8*)((const char*)Ps + w * 4096 + l15 * 256 +
                                   ((mq * 64 + quad * 16) ^ ((l15 & 7) << 4)));
#pragma unroll
      for (int c = 0; c < 8; ++c)
        accp[c] = __builtin_amdgcn_mfma_f32_16x16x32_bf16(pa, vf[c], accp[c], 0, 0, 0);
    }
  }
  // ---- store bf16 partial [n][h*128+d]; n = quad*4+i ----
#pragma unroll
  for (int c = 0; c < 8; ++c)
#pragma unroll
    for (int i = 0; i < 4; ++i)
      part[(long)(n0 + quad * 4 + i) * 1024 + w * 128 + c * 16 + l15] =
          f32_bf16(accp[c][i]);
}

// out = bf16(p0+p1+p2+p3)
__global__ __launch_bounds__(256) void reduce4p_bf16(
    const u16* __restrict__ p0, const u16* __restrict__ p1,
    const u16* __restrict__ p2, const u16* __restrict__ p3, u16* __restrict__ out) {
  long i = (long)blockIdx.x * 256 + threadIdx.x;  // ushort4 idx, 524288 total
  ushort4 a = ((const ushort4*)p0)[i];
  ushort4 b = ((const ushort4*)p1)[i];
  ushort4 c = ((const ushort4*)p2)[i];
  ushort4 d = ((const ushort4*)p3)[i];
  ushort4 o;
  o.x = f32_bf16(bf2f(a.x) + bf2f(b.x) + bf2f(c.x) + bf2f(d.x));
  o.y = f32_bf16(bf2f(a.y) + bf2f(b.y) + bf2f(c.y) + bf2f(d.y));
  o.z = f32_bf16(bf2f(a.z) + bf2f(b.z) + bf2f(c.z) + bf2f(d.z));
  o.w = f32_bf16(bf2f(a.w) + bf2f(b.w) + bf2f(c.w) + bf2f(d.w));
  ((ushort4*)out)[i] = o;
}

// ---- residual + 4 bf16 partials + column-bias + layernorm; fp32 (+bf16) out ----
__global__ __launch_bounds__(256) void ln_residual_p4(
    const float* __restrict__ x,
    const u16* __restrict__ p0, const u16* __restrict__ p1,
    const u16* __restrict__ p2, const u16* __restrict__ p3,
    const float* __restrict__ colb, const float* __restrict__ g, const float* __restrict__ b,
    float* __restrict__ out32, u16* __restrict__ out16) {
  const int row = blockIdx.x, t = threadIdx.x;
  const long base = (long)row * EMB;
  float4 v = ((const float4*)(x + base))[t];
  ushort4 a0 = ((const ushort4*)(p0 + base))[t];
  ushort4 a1 = ((const ushort4*)(p1 + base))[t];
  ushort4 a2 = ((const ushort4*)(p2 + base))[t];
  ushort4 a3 = ((const ushort4*)(p3 + base))[t];
  float4 cb = ((const float4*)colb)[t];
  v.x += bf2f(a0.x) + bf2f(a1.x) + bf2f(a2.x) + bf2f(a3.x) + cb.x;
  v.y += bf2f(a0.y) + bf2f(a1.y) + bf2f(a2.y) + bf2f(a3.y) + cb.y;
  v.z += bf2f(a0.z) + bf2f(a1.z) + bf2f(a2.z) + bf2f(a3.z) + cb.z;
  v.w += bf2f(a0.w) + bf2f(a1.w) + bf2f(a2.w) + bf2f(a3.w) + cb.w;
  float s = v.x + v.y + v.z + v.w;
  float q = v.x * v.x + v.y * v.y + v.z * v.z + v.w * v.w;
#pragma unroll
  for (int off = 32; off > 0; off >>= 1) {
    s += __shfl_xor(s, off);
    q += __shfl_xor(q, off);
  }
  __shared__ float red[8];
  const int wv = t >> 6, lane = t & 63;
  if (lane == 0) { red[wv] = s; red[4 + wv] = q; }
  __syncthreads();
  s = red[0] + red[1] + red[2] + red[3];
  q = red[4] + red[5] + red[6] + red[7];
  const float mean = s * (1.f / EMB);
  const float var = q * (1.f / EMB) - mean * mean;
  const float rstd = rsqrtf(var + 1e-5f);
  float4 gg = ((const float4*)g)[t];
  float4 bb = ((const float4*)b)[t];
  float4 o;
  o.x = (v.x - mean) * rstd * gg.x + bb.x;
  o.y = (v.y - mean) * rstd * gg.y + bb.y;
  o.z = (v.z - mean) * rstd * gg.z + bb.z;
  o.w = (v.w - mean) * rstd * gg.w + bb.w;
  ((float4*)(out32 + base))[t] = o;
  if (out16) {
    ushort4 ho;
    ho.x = f32_bf16(o.x); ho.y = f32_bf16(o.y); ho.z = f32_bf16(o.z); ho.w = f32_bf16(o.w);
    ((ushort4*)(out16 + base))[t] = ho;
  }
}

extern "C" void kernel_launch(void* const* d_in, const int* in_sizes, int n_in,
                              void* d_out, int out_size, void* d_ws, size_t ws_size,
                              hipStream_t stream) {
  const float* x1 = (const float*)d_in[0];
  const float* x2 = (const float*)d_in[1];
  const float* Wq = (const float*)d_in[2];
  const float* bq = (const float*)d_in[3];
  const float* Wk = (const float*)d_in[4];
  const float* bk = (const float*)d_in[5];
  const float* Wv = (const float*)d_in[6];
  const float* bv = (const float*)d_in[7];
  const float* Wo = (const float*)d_in[8];
  const float* bo = (const float*)d_in[9];
  const float* W1 = (const float*)d_in[10];
  const float* b1 = (const float*)d_in[11];
  const float* W2 = (const float*)d_in[12];
  const float* b2 = (const float*)d_in[13];
  const float* g1 = (const float*)d_in[14];
  const float* be1 = (const float*)d_in[15];
  const float* g2 = (const float*)d_in[16];
  const float* be2 = (const float*)d_in[17];

  char* ws = (char*)d_ws;
  const size_t MB = 1ull << 20;
  // bf16 convert region (contiguous, 32 MB):
  u16* x1b = (u16*)(ws + 0 * MB);
  u16* x2b = (u16*)(ws + 4 * MB);
  u16* Wqb = (u16*)(ws + 8 * MB);
  u16* Wkb = (u16*)(ws + 10 * MB);
  u16* Wvb = (u16*)(ws + 12 * MB);
  u16* Wob = (u16*)(ws + 14 * MB);
  u16* W1b = (u16*)(ws + 16 * MB);
  u16* W2b = (u16*)(ws + 24 * MB);
  // attention buffers:
  u16* Qb  = (u16*)(ws + 32 * MB);
  u16* Kb  = (u16*)(ws + 36 * MB);
  u16* Vtb = (u16*)(ws + 40 * MB);   // 4 MB (transposed V: [h*128+d][m], ld 2048)
  u16* attnb = (u16*)(ws + 44 * MB); // 4 MB
  // fused-attn partials (16 MB, in the old P region):
  u16* aP[4] = {(u16*)(ws + 48 * MB), (u16*)(ws + 52 * MB),
                (u16*)(ws + 56 * MB), (u16*)(ws + 60 * MB)};
  // post-attention region (reuses same region AFTER reduce4p consumed aP):
  u16* woP[4] = {(u16*)(ws + 48 * MB), (u16*)(ws + 52 * MB),
                 (u16*)(ws + 56 * MB), (u16*)(ws + 60 * MB)};   // 16 MB
  float* h32  = (float*)(ws + 64 * MB);  // 8 MB
  u16*  h16   = (u16*)(ws + 72 * MB);    // 4 MB
  u16*  ffn1b = (u16*)(ws + 76 * MB);    // 16 MB
  u16* f2P[4] = {(u16*)(ws + 92 * MB), (u16*)(ws + 96 * MB),
                 (u16*)(ws + 100 * MB), (u16*)(ws + 104 * MB)}; // 16 MB -> 108 peak

  // 1. all fp32->bf16 conversions
  CvtArgs ca;
  ca.src[0] = x1; ca.src[1] = x2; ca.src[2] = Wq; ca.src[3] = Wk;
  ca.src[4] = Wv; ca.src[5] = Wo; ca.src[6] = W1; ca.src[7] = W2;
  cvt_all<<<16384, 256, 0, stream>>>(ca, (u16*)ws);

  // 2. Q/K/V projections (one launch, 384 blocks)
  qkv_kernel<<<dim3(8, 16, 3), 256, 0, stream>>>(x1b, x2b, Wqb, Wkb, Wvb, bq, bk, bv, Qb, Kb, Vtb);

  // 3. fused QK^T + softmax(heads) + PV -> 4 bf16 partials (512 blocks, 2/CU)
  attn_fused<<<dim3(128, 4), 512, 0, stream>>>(Qb, Kb, Vtb, aP[0], aP[1], aP[2], aP[3]);

  // 4. attnb = sum of 4 partials
  reduce4p_bf16<<<2048, 256, 0, stream>>>(aP[0], aP[1], aP[2], aP[3], attnb);

  // 5. Wo GEMM split-K x4 (512 blocks), bf16 partials (bias folded into LN)
  gemm_bt_k<<<dim3(8, 16, 4), 256, 0, stream>>>(attnb, Wob, woP[0], nullptr,
                                                256, 1024, 1024, 1024,
                                                256, 256, (long)BS * 1024, 1, 0);

  // 6. h = LN(x1 + sum(woP) + bo)
  ln_residual_p4<<<2048, 256, 0, stream>>>(x1, woP[0], woP[1], woP[2], woP[3],
                                           bo, g1, be1, h32, h16);

  // 7. FFN1 (+bias+relu), 512 blocks
  gemm_bt_k<<<dim3(32, 16, 1), 256, 0, stream>>>(h16, W1b, ffn1b, b1,
                                                 1024, 1024, 1024, 4096,
                                                 0, 0, 0, 1, 1);

  // 8. FFN2 split-K x4 (512 blocks), bf16 partials (bias folded into LN)
  gemm_bt_k<<<dim3(8, 16, 4), 256, 0, stream>>>(ffn1b, W2b, f2P[0], nullptr,
                                                1024, 4096, 4096, 1024,
                                                1024, 1024, (long)BS * 1024, 1, 0);

  // 9. out = LN(h + sum(f2P) + b2)
  ln_residual_p4<<<2048, 256, 0, stream>>>(h32, f2P[0], f2P[1], f2P[2], f2P[3],
                                           b2, g2, be2, (float*)d_out, nullptr);
}

// Round 6
// 370.013 us; speedup vs baseline: 1.2082x; 1.2082x over previous
//
#include <hip/hip_runtime.h>

#define BS 2048
#define EMB 1024
#define NHEAD 8
#define HDIM 128

typedef unsigned short u16;
typedef __attribute__((ext_vector_type(8))) short bf16x8;
typedef __attribute__((ext_vector_type(4))) float f32x4;

__device__ __forceinline__ u16 f32_bf16(float f) {
  unsigned u = __float_as_uint(f);
  u += 0x7fffu + ((u >> 16) & 1u);
  return (u16)(u >> 16);
}
__device__ __forceinline__ float bf2f(u16 x) {
  return __uint_as_float((unsigned)x << 16);
}

__device__ __forceinline__ void gld_lds16(const void* g, void* l) {
  __builtin_amdgcn_global_load_lds(
      (const __attribute__((address_space(1))) void*)g,
      (__attribute__((address_space(3))) void*)l, 16, 0, 0);
}

// ---------------- fp32 -> bf16: ALL weights/activations in ONE kernel ----------
// segs of 256K v4 (1M elems): [0,2)=x1 [2,4)=x2 [4]=Wq [5]=Wk [6]=Wv [7]=Wo
// [8,12)=W1 [12,16)=W2
struct CvtArgs { const float* src[8]; };
__global__ __launch_bounds__(256) void cvt_all(CvtArgs a, u16* __restrict__ dst) {
  long i = (long)blockIdx.x * 256 + threadIdx.x;  // v4 index
  int seg = (int)(i >> 18);
  const float* src; long b;
  if (seg < 2)       { src = a.src[0]; b = 0; }
  else if (seg < 4)  { src = a.src[1]; b = 2L << 18; }
  else if (seg == 4) { src = a.src[2]; b = 4L << 18; }
  else if (seg == 5) { src = a.src[3]; b = 5L << 18; }
  else if (seg == 6) { src = a.src[4]; b = 6L << 18; }
  else if (seg == 7) { src = a.src[5]; b = 7L << 18; }
  else if (seg < 12) { src = a.src[6]; b = 8L << 18; }
  else               { src = a.src[7]; b = 12L << 18; }
  float4 v = ((const float4*)src)[i - b];
  ushort4 o;
  o.x = f32_bf16(v.x); o.y = f32_bf16(v.y); o.z = f32_bf16(v.z); o.w = f32_bf16(v.w);
  ((ushort4*)dst)[i] = o;
}

// ---------------- GEMM core: C = A @ B^T (+bias), 128x128 tile, BK=32 ----------
// mode: 0 = fp32 out, 1 = bf16 out, 2 = bf16 transposed store (Ct[n][m])
__device__ __forceinline__ void gemm_core(
    const u16* __restrict__ A, const u16* __restrict__ B, void* __restrict__ Cp,
    const float* __restrict__ bias, int K, int lda, int ldb, int ldc,
    long cbase, int mode, int relu, int m0, int n0) {
  __shared__ __align__(16) u16 As[128 * 32];
  __shared__ __align__(16) u16 Bs[128 * 32];
  const int t = threadIdx.x;
  const int lane = t & 63, l15 = lane & 15, quad = lane >> 4;
  const int wv = t >> 6, wr = wv & 1, wc = wv >> 1;
  const int wbase = t & ~63;

  f32x4 acc[4][4];
#pragma unroll
  for (int r = 0; r < 4; ++r)
#pragma unroll
    for (int c = 0; c < 4; ++c) acc[r][c] = (f32x4){0.f, 0.f, 0.f, 0.f};

  for (int k0 = 0; k0 < K; k0 += 32) {
#pragma unroll
    for (int i = 0; i < 2; ++i) {
      int s = i * 256 + t;
      gld_lds16(A + (long)(m0 + (s >> 2)) * lda + k0 + (s & 3) * 8,
                As + (i * 256 + wbase) * 8);
    }
#pragma unroll
    for (int i = 0; i < 2; ++i) {
      int s = i * 256 + t;
      gld_lds16(B + (long)(n0 + (s >> 2)) * ldb + k0 + (s & 3) * 8,
                Bs + (i * 256 + wbase) * 8);
    }
    __syncthreads();
    bf16x8 fa[4], fb[4];
#pragma unroll
    for (int r = 0; r < 4; ++r)
      fa[r] = *(const bf16x8*)&As[(wr * 64 + r * 16 + l15) * 32 + quad * 8];
#pragma unroll
    for (int c = 0; c < 4; ++c)
      fb[c] = *(const bf16x8*)&Bs[(wc * 64 + c * 16 + l15) * 32 + quad * 8];
#pragma unroll
    for (int r = 0; r < 4; ++r)
#pragma unroll
      for (int c = 0; c < 4; ++c)
        acc[r][c] = __builtin_amdgcn_mfma_f32_16x16x32_bf16(fa[r], fb[c], acc[r][c], 0, 0, 0);
    __syncthreads();
  }

#pragma unroll
  for (int r = 0; r < 4; ++r)
#pragma unroll
    for (int c = 0; c < 4; ++c) {
      const int m = m0 + wr * 64 + r * 16 + quad * 4;
      const int n = n0 + wc * 64 + c * 16 + l15;
      const float bv = bias ? bias[n] : 0.f;
      f32x4 v = acc[r][c];
      if (mode == 2) {
        ushort4 o;
        o.x = f32_bf16(v[0] + bv);
        o.y = f32_bf16(v[1] + bv);
        o.z = f32_bf16(v[2] + bv);
        o.w = f32_bf16(v[3] + bv);
        *(ushort4*)((u16*)Cp + cbase + (long)n * ldc + m) = o;
      } else {
#pragma unroll
        for (int i = 0; i < 4; ++i) {
          float x = v[i] + bv;
          if (relu) x = fmaxf(x, 0.f);
          if (mode == 0)
            ((float*)Cp)[cbase + (long)(m + i) * ldc + n] = x;
          else
            ((u16*)Cp)[cbase + (long)(m + i) * ldc + n] = f32_bf16(x);
        }
      }
    }
}

// generic z-batched GEMM (linear z offsets in elements)
__global__ __launch_bounds__(256) void gemm_bt_k(
    const u16* __restrict__ A, const u16* __restrict__ B, void* __restrict__ C,
    const float* __restrict__ bias, int K, int lda, int ldb, int ldc,
    long aOffZ, long bOffZ, long cOffZ, int mode, int relu) {
  gemm_core(A + (long)blockIdx.z * aOffZ, B + (long)blockIdx.z * bOffZ, C, bias,
            K, lda, ldb, ldc, (long)blockIdx.z * cOffZ, mode, relu,
            blockIdx.y * 128, blockIdx.x * 128);
}

// Q/K/V projections in one launch: z=0 Q(x1), z=1 K(x2), z=2 V(x2, transposed out)
__global__ __launch_bounds__(256) void qkv_kernel(
    const u16* __restrict__ x1b, const u16* __restrict__ x2b,
    const u16* __restrict__ Wqb, const u16* __restrict__ Wkb, const u16* __restrict__ Wvb,
    const float* __restrict__ bq, const float* __restrict__ bk, const float* __restrict__ bv,
    u16* __restrict__ Qb, u16* __restrict__ Kb, u16* __restrict__ Vt) {
  const int z = blockIdx.z;
  const u16* A = (z == 0) ? x1b : x2b;
  const u16* B = (z == 0) ? Wqb : (z == 1) ? Wkb : Wvb;
  void* C = (z == 0) ? (void*)Qb : (z == 1) ? (void*)Kb : (void*)Vt;
  const float* bias = (z == 0) ? bq : (z == 1) ? bk : bv;
  const int mode = (z == 2) ? 2 : 1;
  const int ldc = (z == 2) ? 2048 : 1024;
  gemm_core(A, B, C, bias, 1024, 1024, 1024, ldc, 0, mode, 0,
            blockIdx.y * 128, blockIdx.x * 128);
}

// ---------------- fused attention: QK^T + softmax(heads) + PV -----------------
// grid: x = n-block (64 of 32 rows), y = m-split (4 of 512). 1024 threads,
// 16 waves (4/SIMD), LDS 144 KB, 1 block/CU. Same staging pipeline as the
// verified 512-thread version; per-wave compute halved for latency hiding.
// Wave w: mw = w&7 (m-chunk / head), nh = w>>3 (n-half).
// 2-phase pipelined staging: per (it, h) step one combined 40 KB slab
//   K[128m][128k_h] + Q[32n][128k_h] into a double buffer via async
//   global_load_lds, XOR-swizzled through the pre-swizzled global source.
//   Per step: sync (drains stage issued LAST step, overlapped with compute)
//   -> issue stage(next, buf^1) -> compute(cur). One barrier/step.
// accs[8] per lane (all heads, m=mw chunk, n-half nh) -> per-lane softmax.
// P -> LDS [h][32n][128m] bf16 XOR-swizzled; PV: head mw, n-half nh, V direct
// global batched vf[8] per mq. Partials reduced by reduce4p_bf16.
__global__ __launch_bounds__(1024, 4) void attn_fused(
    const u16* __restrict__ Q, const u16* __restrict__ Km, const u16* __restrict__ Vt,
    u16* __restrict__ p0, u16* __restrict__ p1, u16* __restrict__ p2, u16* __restrict__ p3) {
  __shared__ __align__(16) u16 KQ[2 * 20480];     // 2 x (128+32) rows x 128 = 80 KB
  __shared__ __align__(16) u16 Ps[8 * 32 * 128];  // 64 KB, [h][n][m] swizzled
  const int t = threadIdx.x;
  const int lane = t & 63, l15 = lane & 15, quad = lane >> 4;
  const int w = t >> 6;
  const int mw = w & 7, nh = w >> 3;
  const int n0 = blockIdx.x * 32;
  const int mz = blockIdx.y * 512;
  u16* part = (blockIdx.y == 0) ? p0 : (blockIdx.y == 1) ? p1 : (blockIdx.y == 2) ? p2 : p3;

  // stage step snum (= it*8 + h) into buffer bsel.
  // LDS granule G (16B): row r = G>>4 (0..127 = K row m, 128..159 = Q row n),
  // in-row granule g = G&15, data = row[(g ^ (r&7))*8 ..] (pre-swizzled source).
  auto stage = [&](int snum, int bsel) {
    const int sh = (snum & 7) * 128;
    const int smb = mz + (snum >> 3) * 128;
#pragma unroll
    for (int i = 0; i < 3; ++i) {
      int G = i * 1024 + t;
      if (G < 2560) {  // wave-uniform guard (i==2 covers threads < 512 only)
        int r = G >> 4, g = G & 15;
        const u16* src;
        if (i < 2) src = Km + (long)(smb + r) * 1024 + sh + ((g ^ (r & 7)) << 3);
        else       src = Q + (long)(n0 + r - 128) * 1024 + sh + ((g ^ (r & 7)) << 3);
        gld_lds16(src, KQ + bsel * 20480 + G * 8);
      }
    }
  };

  f32x4 accp[8];
#pragma unroll
  for (int c = 0; c < 8; ++c) accp[c] = (f32x4){0.f, 0.f, 0.f, 0.f};

  int b = 0;
  stage(0, 0);

  const int m = mw * 16 + l15;      // this lane's m within the 128 m-tile
  const int nq = nh * 16 + l15;     // this lane's n within the 32-row tile
  const int sw3 = (l15 & 7) << 3;   // element-granular XOR (m&7 == nq&7 == l15&7)
  const int sw4 = (nq & 7) << 4;    // 16B-granular XOR for Ps

  for (int it = 0; it < 4; ++it) {
    const int mb = mz + it * 128;
    f32x4 accs[8];
#pragma unroll
    for (int h = 0; h < 8; ++h) accs[h] = (f32x4){0.f, 0.f, 0.f, 0.f};

#pragma unroll
    for (int h = 0; h < 8; ++h) {
      __syncthreads();  // drains stage(cur) (vmcnt0+lgkm0), closes prev readers
      int ns = it * 8 + h + 1;
      if (ns < 32) stage(ns, b ^ 1);  // overlaps with compute below
      const u16* kb = KQ + b * 20480;
      const u16* qb = kb + 128 * 128;
#pragma unroll
      for (int kk = 0; kk < 4; ++kk) {
        int ko = (kk * 32 + quad * 8) ^ sw3;
        bf16x8 fa = *(const bf16x8*)&kb[m * 128 + ko];
        bf16x8 fb = *(const bf16x8*)&qb[nq * 128 + ko];
        accs[h] = __builtin_amdgcn_mfma_f32_16x16x32_bf16(fa, fb, accs[h], 0, 0, 0);
      }
      b ^= 1;
    }

    // ---- softmax over heads, per-lane; i indexes m (rows of S^T) ----
    const float scale = 0.08838834764831845f;  // 1/sqrt(128)
#pragma unroll
    for (int i = 0; i < 4; ++i) {
      float mx = accs[0][i];
#pragma unroll
      for (int h = 1; h < 8; ++h) mx = fmaxf(mx, accs[h][i]);
      float sum = 0.f;
#pragma unroll
      for (int h = 0; h < 8; ++h) {
        float e = __expf((accs[h][i] - mx) * scale);
        accs[h][i] = e;
        sum += e;
      }
      float inv = 1.f / sum;
#pragma unroll
      for (int h = 0; h < 8; ++h) accs[h][i] *= inv;
    }
    // ---- P -> LDS, m-packed ushort4, swizzled ----
#pragma unroll
    for (int h = 0; h < 8; ++h) {
      ushort4 o;
      o.x = f32_bf16(accs[h][0]);
      o.y = f32_bf16(accs[h][1]);
      o.z = f32_bf16(accs[h][2]);
      o.w = f32_bf16(accs[h][3]);
      *(ushort4*)((char*)Ps + h * 8192 + nq * 256 + ((mw * 32 + quad * 8) ^ sw4)) = o;
    }
    __syncthreads();  // Ps ready (PV reads of prev it all closed by h-loop barriers)
    // ---- PV: head mw, n-half nh; C[n16][d128] += P[n][m128] * Vt[d][m128]^T ----
    // (overlaps the already-issued stage of next it's h=0 slab)
#pragma unroll
    for (int mq = 0; mq < 4; ++mq) {
      bf16x8 vf[8];
#pragma unroll
      for (int c = 0; c < 8; ++c)
        vf[c] = *(const bf16x8*)&Vt[(long)(mw * 128 + c * 16 + l15) * 2048 +
                                    mb + mq * 32 + quad * 8];
      bf16x8 pa = *(const bf16x8*)((const char*)Ps + mw * 8192 + nq * 256 +
                                   ((mq * 64 + quad * 16) ^ sw4));
#pragma unroll
      for (int c = 0; c < 8; ++c)
        accp[c] = __builtin_amdgcn_mfma_f32_16x16x32_bf16(pa, vf[c], accp[c], 0, 0, 0);
    }
  }
  // ---- store bf16 partial [n][h*128+d] ----
#pragma unroll
  for (int c = 0; c < 8; ++c)
#pragma unroll
    for (int i = 0; i < 4; ++i)
      part[(long)(n0 + nh * 16 + quad * 4 + i) * 1024 + mw * 128 + c * 16 + l15] =
          f32_bf16(accp[c][i]);
}

// out = bf16(p0+p1+p2+p3)
__global__ __launch_bounds__(256) void reduce4p_bf16(
    const u16* __restrict__ p0, const u16* __restrict__ p1,
    const u16* __restrict__ p2, const u16* __restrict__ p3, u16* __restrict__ out) {
  long i = (long)blockIdx.x * 256 + threadIdx.x;  // ushort4 idx, 524288 total
  ushort4 a = ((const ushort4*)p0)[i];
  ushort4 b = ((const ushort4*)p1)[i];
  ushort4 c = ((const ushort4*)p2)[i];
  ushort4 d = ((const ushort4*)p3)[i];
  ushort4 o;
  o.x = f32_bf16(bf2f(a.x) + bf2f(b.x) + bf2f(c.x) + bf2f(d.x));
  o.y = f32_bf16(bf2f(a.y) + bf2f(b.y) + bf2f(c.y) + bf2f(d.y));
  o.z = f32_bf16(bf2f(a.z) + bf2f(b.z) + bf2f(c.z) + bf2f(d.z));
  o.w = f32_bf16(bf2f(a.w) + bf2f(b.w) + bf2f(c.w) + bf2f(d.w));
  ((ushort4*)out)[i] = o;
}

// ---- residual + 4 bf16 partials + column-bias + layernorm; fp32 (+bf16) out ----
__global__ __launch_bounds__(256) void ln_residual_p4(
    const float* __restrict__ x,
    const u16* __restrict__ p0, const u16* __restrict__ p1,
    const u16* __restrict__ p2, const u16* __restrict__ p3,
    const float* __restrict__ colb, const float* __restrict__ g, const float* __restrict__ b,
    float* __restrict__ out32, u16* __restrict__ out16) {
  const int row = blockIdx.x, t = threadIdx.x;
  const long base = (long)row * EMB;
  float4 v = ((const float4*)(x + base))[t];
  ushort4 a0 = ((const ushort4*)(p0 + base))[t];
  ushort4 a1 = ((const ushort4*)(p1 + base))[t];
  ushort4 a2 = ((const ushort4*)(p2 + base))[t];
  ushort4 a3 = ((const ushort4*)(p3 + base))[t];
  float4 cb = ((const float4*)colb)[t];
  v.x += bf2f(a0.x) + bf2f(a1.x) + bf2f(a2.x) + bf2f(a3.x) + cb.x;
  v.y += bf2f(a0.y) + bf2f(a1.y) + bf2f(a2.y) + bf2f(a3.y) + cb.y;
  v.z += bf2f(a0.z) + bf2f(a1.z) + bf2f(a2.z) + bf2f(a3.z) + cb.z;
  v.w += bf2f(a0.w) + bf2f(a1.w) + bf2f(a2.w) + bf2f(a3.w) + cb.w;
  float s = v.x + v.y + v.z + v.w;
  float q = v.x * v.x + v.y * v.y + v.z * v.z + v.w * v.w;
#pragma unroll
  for (int off = 32; off > 0; off >>= 1) {
    s += __shfl_xor(s, off);
    q += __shfl_xor(q, off);
  }
  __shared__ float red[8];
  const int wv = t >> 6, lane = t & 63;
  if (lane == 0) { red[wv] = s; red[4 + wv] = q; }
  __syncthreads();
  s = red[0] + red[1] + red[2] + red[3];
  q = red[4] + red[5] + red[6] + red[7];
  const float mean = s * (1.f / EMB);
  const float var = q * (1.f / EMB) - mean * mean;
  const float rstd = rsqrtf(var + 1e-5f);
  float4 gg = ((const float4*)g)[t];
  float4 bb = ((const float4*)b)[t];
  float4 o;
  o.x = (v.x - mean) * rstd * gg.x + bb.x;
  o.y = (v.y - mean) * rstd * gg.y + bb.y;
  o.z = (v.z - mean) * rstd * gg.z + bb.z;
  o.w = (v.w - mean) * rstd * gg.w + bb.w;
  ((float4*)(out32 + base))[t] = o;
  if (out16) {
    ushort4 ho;
    ho.x = f32_bf16(o.x); ho.y = f32_bf16(o.y); ho.z = f32_bf16(o.z); ho.w = f32_bf16(o.w);
    ((ushort4*)(out16 + base))[t] = ho;
  }
}

extern "C" void kernel_launch(void* const* d_in, const int* in_sizes, int n_in,
                              void* d_out, int out_size, void* d_ws, size_t ws_size,
                              hipStream_t stream) {
  const float* x1 = (const float*)d_in[0];
  const float* x2 = (const float*)d_in[1];
  const float* Wq = (const float*)d_in[2];
  const float* bq = (const float*)d_in[3];
  const float* Wk = (const float*)d_in[4];
  const float* bk = (const float*)d_in[5];
  const float* Wv = (const float*)d_in[6];
  const float* bv = (const float*)d_in[7];
  const float* Wo = (const float*)d_in[8];
  const float* bo = (const float*)d_in[9];
  const float* W1 = (const float*)d_in[10];
  const float* b1 = (const float*)d_in[11];
  const float* W2 = (const float*)d_in[12];
  const float* b2 = (const float*)d_in[13];
  const float* g1 = (const float*)d_in[14];
  const float* be1 = (const float*)d_in[15];
  const float* g2 = (const float*)d_in[16];
  const float* be2 = (const float*)d_in[17];

  char* ws = (char*)d_ws;
  const size_t MB = 1ull << 20;
  // bf16 convert region (contiguous, 32 MB):
  u16* x1b = (u16*)(ws + 0 * MB);
  u16* x2b = (u16*)(ws + 4 * MB);
  u16* Wqb = (u16*)(ws + 8 * MB);
  u16* Wkb = (u16*)(ws + 10 * MB);
  u16* Wvb = (u16*)(ws + 12 * MB);
  u16* Wob = (u16*)(ws + 14 * MB);
  u16* W1b = (u16*)(ws + 16 * MB);
  u16* W2b = (u16*)(ws + 24 * MB);
  // attention buffers:
  u16* Qb  = (u16*)(ws + 32 * MB);
  u16* Kb  = (u16*)(ws + 36 * MB);
  u16* Vtb = (u16*)(ws + 40 * MB);   // 4 MB (transposed V: [h*128+d][m], ld 2048)
  u16* attnb = (u16*)(ws + 44 * MB); // 4 MB
  // fused-attn partials (16 MB, in the old P region):
  u16* aP[4] = {(u16*)(ws + 48 * MB), (u16*)(ws + 52 * MB),
                (u16*)(ws + 56 * MB), (u16*)(ws + 60 * MB)};
  // post-attention region (reuses same region AFTER reduce4p consumed aP):
  u16* woP[4] = {(u16*)(ws + 48 * MB), (u16*)(ws + 52 * MB),
                 (u16*)(ws + 56 * MB), (u16*)(ws + 60 * MB)};   // 16 MB
  float* h32  = (float*)(ws + 64 * MB);  // 8 MB
  u16*  h16   = (u16*)(ws + 72 * MB);    // 4 MB
  u16*  ffn1b = (u16*)(ws + 76 * MB);    // 16 MB
  u16* f2P[4] = {(u16*)(ws + 92 * MB), (u16*)(ws + 96 * MB),
                 (u16*)(ws + 100 * MB), (u16*)(ws + 104 * MB)}; // 16 MB -> 108 peak

  // 1. all fp32->bf16 conversions
  CvtArgs ca;
  ca.src[0] = x1; ca.src[1] = x2; ca.src[2] = Wq; ca.src[3] = Wk;
  ca.src[4] = Wv; ca.src[5] = Wo; ca.src[6] = W1; ca.src[7] = W2;
  cvt_all<<<16384, 256, 0, stream>>>(ca, (u16*)ws);

  // 2. Q/K/V projections (one launch, 384 blocks)
  qkv_kernel<<<dim3(8, 16, 3), 256, 0, stream>>>(x1b, x2b, Wqb, Wkb, Wvb, bq, bk, bv, Qb, Kb, Vtb);

  // 3. fused QK^T + softmax(heads) + PV -> 4 bf16 partials (256 blocks, 1/CU)
  attn_fused<<<dim3(64, 4), 1024, 0, stream>>>(Qb, Kb, Vtb, aP[0], aP[1], aP[2], aP[3]);

  // 4. attnb = sum of 4 partials
  reduce4p_bf16<<<2048, 256, 0, stream>>>(aP[0], aP[1], aP[2], aP[3], attnb);

  // 5. Wo GEMM split-K x4 (512 blocks), bf16 partials (bias folded into LN)
  gemm_bt_k<<<dim3(8, 16, 4), 256, 0, stream>>>(attnb, Wob, woP[0], nullptr,
                                                256, 1024, 1024, 1024,
                                                256, 256, (long)BS * 1024, 1, 0);

  // 6. h = LN(x1 + sum(woP) + bo)
  ln_residual_p4<<<2048, 256, 0, stream>>>(x1, woP[0], woP[1], woP[2], woP[3],
                                           bo, g1, be1, h32, h16);

  // 7. FFN1 (+bias+relu), 512 blocks
  gemm_bt_k<<<dim3(32, 16, 1), 256, 0, stream>>>(h16, W1b, ffn1b, b1,
                                                 1024, 1024, 1024, 4096,
                                                 0, 0, 0, 1, 1);

  // 8. FFN2 split-K x4 (512 blocks), bf16 partials (bias folded into LN)
  gemm_bt_k<<<dim3(8, 16, 4), 256, 0, stream>>>(ffn1b, W2b, f2P[0], nullptr,
                                                1024, 4096, 4096, 1024,
                                                1024, 1024, (long)BS * 1024, 1, 0);

  // 9. out = LN(h + sum(f2P) + b2)
  ln_residual_p4<<<2048, 256, 0, stream>>>(h32, f2P[0], f2P[1], f2P[2], f2P[3],
                                           b2, g2, be2, (float*)d_out, nullptr);
}

// Round 8
// 357.760 us; speedup vs baseline: 1.2496x; 1.0342x over previous
//
#include <hip/hip_runtime.h>

#define BS 2048
#define EMB 1024
#define NHEAD 8
#define HDIM 128

typedef unsigned short u16;
typedef __attribute__((ext_vector_type(8))) short bf16x8;
typedef __attribute__((ext_vector_type(4))) float f32x4;

__device__ __forceinline__ u16 f32_bf16(float f) {
  unsigned u = __float_as_uint(f);
  u += 0x7fffu + ((u >> 16) & 1u);
  return (u16)(u >> 16);
}
__device__ __forceinline__ float bf2f(u16 x) {
  return __uint_as_float((unsigned)x << 16);
}

__device__ __forceinline__ void gld_lds16(const void* g, void* l) {
  __builtin_amdgcn_global_load_lds(
      (const __attribute__((address_space(1))) void*)g,
      (__attribute__((address_space(3))) void*)l, 16, 0, 0);
}

// ---------------- fp32 -> bf16: ALL weights/activations in ONE kernel ----------
// segs of 256K v4 (1M elems): [0,2)=x1 [2,4)=x2 [4]=Wq [5]=Wk [6]=Wv [7]=Wo
// [8,12)=W1 [12,16)=W2
struct CvtArgs { const float* src[8]; };
__global__ __launch_bounds__(256) void cvt_all(CvtArgs a, u16* __restrict__ dst) {
  long i = (long)blockIdx.x * 256 + threadIdx.x;  // v4 index
  int seg = (int)(i >> 18);
  const float* src; long b;
  if (seg < 2)       { src = a.src[0]; b = 0; }
  else if (seg < 4)  { src = a.src[1]; b = 2L << 18; }
  else if (seg == 4) { src = a.src[2]; b = 4L << 18; }
  else if (seg == 5) { src = a.src[3]; b = 5L << 18; }
  else if (seg == 6) { src = a.src[4]; b = 6L << 18; }
  else if (seg == 7) { src = a.src[5]; b = 7L << 18; }
  else if (seg < 12) { src = a.src[6]; b = 8L << 18; }
  else               { src = a.src[7]; b = 12L << 18; }
  float4 v = ((const float4*)src)[i - b];
  ushort4 o;
  o.x = f32_bf16(v.x); o.y = f32_bf16(v.y); o.z = f32_bf16(v.z); o.w = f32_bf16(v.w);
  ((ushort4*)dst)[i] = o;
}

// ---------------- GEMM core: C = A @ B^T (+bias), 128x128 tile, BK=32 ----------
// mode: 0 = fp32 out, 1 = bf16 out, 2 = bf16 transposed store (Ct[n][m])
__device__ __forceinline__ void gemm_core(
    const u16* __restrict__ A, const u16* __restrict__ B, void* __restrict__ Cp,
    const float* __restrict__ bias, int K, int lda, int ldb, int ldc,
    long cbase, int mode, int relu, int m0, int n0) {
  __shared__ __align__(16) u16 As[128 * 32];
  __shared__ __align__(16) u16 Bs[128 * 32];
  const int t = threadIdx.x;
  const int lane = t & 63, l15 = lane & 15, quad = lane >> 4;
  const int wv = t >> 6, wr = wv & 1, wc = wv >> 1;
  const int wbase = t & ~63;

  f32x4 acc[4][4];
#pragma unroll
  for (int r = 0; r < 4; ++r)
#pragma unroll
    for (int c = 0; c < 4; ++c) acc[r][c] = (f32x4){0.f, 0.f, 0.f, 0.f};

  for (int k0 = 0; k0 < K; k0 += 32) {
#pragma unroll
    for (int i = 0; i < 2; ++i) {
      int s = i * 256 + t;
      gld_lds16(A + (long)(m0 + (s >> 2)) * lda + k0 + (s & 3) * 8,
                As + (i * 256 + wbase) * 8);
    }
#pragma unroll
    for (int i = 0; i < 2; ++i) {
      int s = i * 256 + t;
      gld_lds16(B + (long)(n0 + (s >> 2)) * ldb + k0 + (s & 3) * 8,
                Bs + (i * 256 + wbase) * 8);
    }
    __syncthreads();
    bf16x8 fa[4], fb[4];
#pragma unroll
    for (int r = 0; r < 4; ++r)
      fa[r] = *(const bf16x8*)&As[(wr * 64 + r * 16 + l15) * 32 + quad * 8];
#pragma unroll
    for (int c = 0; c < 4; ++c)
      fb[c] = *(const bf16x8*)&Bs[(wc * 64 + c * 16 + l15) * 32 + quad * 8];
#pragma unroll
    for (int r = 0; r < 4; ++r)
#pragma unroll
      for (int c = 0; c < 4; ++c)
        acc[r][c] = __builtin_amdgcn_mfma_f32_16x16x32_bf16(fa[r], fb[c], acc[r][c], 0, 0, 0);
    __syncthreads();
  }

#pragma unroll
  for (int r = 0; r < 4; ++r)
#pragma unroll
    for (int c = 0; c < 4; ++c) {
      const int m = m0 + wr * 64 + r * 16 + quad * 4;
      const int n = n0 + wc * 64 + c * 16 + l15;
      const float bv = bias ? bias[n] : 0.f;
      f32x4 v = acc[r][c];
      if (mode == 2) {
        ushort4 o;
        o.x = f32_bf16(v[0] + bv);
        o.y = f32_bf16(v[1] + bv);
        o.z = f32_bf16(v[2] + bv);
        o.w = f32_bf16(v[3] + bv);
        *(ushort4*)((u16*)Cp + cbase + (long)n * ldc + m) = o;
      } else {
#pragma unroll
        for (int i = 0; i < 4; ++i) {
          float x = v[i] + bv;
          if (relu) x = fmaxf(x, 0.f);
          if (mode == 0)
            ((float*)Cp)[cbase + (long)(m + i) * ldc + n] = x;
          else
            ((u16*)Cp)[cbase + (long)(m + i) * ldc + n] = f32_bf16(x);
        }
      }
    }
}

// generic z-batched GEMM (linear z offsets in elements)
__global__ __launch_bounds__(256) void gemm_bt_k(
    const u16* __restrict__ A, const u16* __restrict__ B, void* __restrict__ C,
    const float* __restrict__ bias, int K, int lda, int ldb, int ldc,
    long aOffZ, long bOffZ, long cOffZ, int mode, int relu) {
  gemm_core(A + (long)blockIdx.z * aOffZ, B + (long)blockIdx.z * bOffZ, C, bias,
            K, lda, ldb, ldc, (long)blockIdx.z * cOffZ, mode, relu,
            blockIdx.y * 128, blockIdx.x * 128);
}

// Q/K/V projections in one launch: z=0 Q(x1), z=1 K(x2), z=2 V(x2, transposed out)
__global__ __launch_bounds__(256) void qkv_kernel(
    const u16* __restrict__ x1b, const u16* __restrict__ x2b,
    const u16* __restrict__ Wqb, const u16* __restrict__ Wkb, const u16* __restrict__ Wvb,
    const float* __restrict__ bq, const float* __restrict__ bk, const float* __restrict__ bv,
    u16* __restrict__ Qb, u16* __restrict__ Kb, u16* __restrict__ Vt) {
  const int z = blockIdx.z;
  const u16* A = (z == 0) ? x1b : x2b;
  const u16* B = (z == 0) ? Wqb : (z == 1) ? Wkb : Wvb;
  void* C = (z == 0) ? (void*)Qb : (z == 1) ? (void*)Kb : (void*)Vt;
  const float* bias = (z == 0) ? bq : (z == 1) ? bk : bv;
  const int mode = (z == 2) ? 2 : 1;
  const int ldc = (z == 2) ? 2048 : 1024;
  gemm_core(A, B, C, bias, 1024, 1024, 1024, ldc, 0, mode, 0,
            blockIdx.y * 128, blockIdx.x * 128);
}

// ---------------- fused attention: QK^T + softmax(heads) + PV -----------------
// grid: x = n-block (64 of 32 rows), y = m-split (8 of 256). 512 threads,
// 8 waves, LDS 80 KB -> 2 blocks/CU (independent barriers: one block computes
// while the other drains -- the TLP mechanism R4 lacked at 144 KB).
// Same verified 2-phase staging pipeline as R4, m-tile shrunk 128->64:
//   per (it, h) step one slab K[64m][128k_h] + Q[32n][128k_h] = 24 KB into a
//   48 KB double buffer via async global_load_lds, XOR pre-swizzled source.
//   Per step: sync (drains stage issued LAST step) -> stage(next) -> compute.
// Scores: wave w: m-chunk mw=w&3 (16 m), n-half nh=w>>2 (16 n); accs[8] holds
// all heads per lane -> per-lane softmax. P -> Ps[8][32][64] bf16 swizzled
// (32 KB, 4096 B/head). PV: wave w owns head w (both n-halves, accp[2][8]),
// V direct-global batched vf[8] per mq (2 mq of k=32).
// 8 partials (one per m-split) reduced by reduce8p_bf16.
__global__ __launch_bounds__(512, 4) void attn_fused(
    const u16* __restrict__ Q, const u16* __restrict__ Km, const u16* __restrict__ Vt,
    u16* __restrict__ aP) {
  __shared__ __align__(16) u16 KQ[2 * 12288];     // 2 x (64+32) rows x 128 = 48 KB
  __shared__ __align__(16) u16 Ps[8 * 32 * 64];   // 32 KB, [h][n][m] swizzled
  const int t = threadIdx.x;
  const int lane = t & 63, l15 = lane & 15, quad = lane >> 4;
  const int w = t >> 6;
  const int mw = w & 3, nh = w >> 2;
  const int n0 = blockIdx.x * 32;
  const int mz = blockIdx.y * 256;
  u16* part = aP + (long)blockIdx.y * BS * 1024;

  // stage step snum (= it*8 + h) into buffer bsel.
  // LDS granule G (16B): row r = G>>4 (0..63 = K row m, 64..95 = Q row n),
  // in-row granule g = G&15, data = row[(g ^ (r&7))*8 ..] (pre-swizzled source).
  // (Q rows: r = 64+n, 64 == 0 mod 8, so r&7 == n&7 -- swizzle consistent.)
  auto stage = [&](int snum, int bsel) {
    const int sh = (snum & 7) * 128;
    const int smb = mz + (snum >> 3) * 64;
#pragma unroll
    for (int i = 0; i < 3; ++i) {
      int G = i * 512 + t;
      int r = G >> 4, g = G & 15;
      const u16* src;
      if (i < 2) src = Km + (long)(smb + r) * 1024 + sh + ((g ^ (r & 7)) << 3);
      else       src = Q + (long)(n0 + r - 64) * 1024 + sh + ((g ^ (r & 7)) << 3);
      gld_lds16(src, KQ + bsel * 12288 + G * 8);
    }
  };

  f32x4 accp[2][8];
#pragma unroll
  for (int r = 0; r < 2; ++r)
#pragma unroll
    for (int c = 0; c < 8; ++c) accp[r][c] = (f32x4){0.f, 0.f, 0.f, 0.f};

  int b = 0;
  stage(0, 0);

  const int m = mw * 16 + l15;      // lane's m within the 64 m-tile
  const int nq = nh * 16 + l15;     // lane's n within the 32-row tile
  const int sw3 = (l15 & 7) << 3;   // element XOR for KQ reads (m&7 == nq&7 == l15&7)
  const int sw4 = (l15 & 7) << 4;   // 16B-granular XOR for Ps byte offsets

  for (int it = 0; it < 4; ++it) {
    const int mb = mz + it * 64;
    f32x4 accs[8];
#pragma unroll
    for (int h = 0; h < 8; ++h) accs[h] = (f32x4){0.f, 0.f, 0.f, 0.f};

#pragma unroll
    for (int h = 0; h < 8; ++h) {
      __syncthreads();  // drains stage(cur) (vmcnt0), closes prev readers
      int ns = it * 8 + h + 1;
      if (ns < 32) stage(ns, b ^ 1);  // overlaps with compute below
      const u16* kb = KQ + b * 12288;
      const u16* qb = kb + 64 * 128;
#pragma unroll
      for (int kk = 0; kk < 4; ++kk) {
        int ko = (kk * 32 + quad * 8) ^ sw3;
        bf16x8 fa = *(const bf16x8*)&kb[m * 128 + ko];
        bf16x8 fb = *(const bf16x8*)&qb[nq * 128 + ko];
        accs[h] = __builtin_amdgcn_mfma_f32_16x16x32_bf16(fa, fb, accs[h], 0, 0, 0);
      }
      b ^= 1;
    }

    // ---- softmax over heads, per-lane; i indexes m (rows of S^T) ----
    const float scale = 0.08838834764831845f;  // 1/sqrt(128)
#pragma unroll
    for (int i = 0; i < 4; ++i) {
      float mx = accs[0][i];
#pragma unroll
      for (int h = 1; h < 8; ++h) mx = fmaxf(mx, accs[h][i]);
      float sum = 0.f;
#pragma unroll
      for (int h = 0; h < 8; ++h) {
        float e = __expf((accs[h][i] - mx) * scale);
        accs[h][i] = e;
        sum += e;
      }
      float inv = 1.f / sum;
#pragma unroll
      for (int h = 0; h < 8; ++h) accs[h][i] *= inv;
    }
    // ---- P -> LDS, m-packed ushort4, swizzled; 4096 B/head, 128 B/row ----
#pragma unroll
    for (int h = 0; h < 8; ++h) {
      ushort4 o;
      o.x = f32_bf16(accs[h][0]);
      o.y = f32_bf16(accs[h][1]);
      o.z = f32_bf16(accs[h][2]);
      o.w = f32_bf16(accs[h][3]);
      *(ushort4*)((char*)Ps + h * 4096 + nq * 128 + ((mw * 32 + quad * 8) ^ sw4)) = o;
    }
    __syncthreads();  // Ps ready (prev PV readers closed by h-loop barriers)
    // ---- PV: head w; C[n32][d128] += P[n][m64] * Vt[d][m64]^T ----
    // (overlaps the already-issued stage of next it's h=0 slab)
#pragma unroll
    for (int mq = 0; mq < 2; ++mq) {
      bf16x8 vf[8];
#pragma unroll
      for (int c = 0; c < 8; ++c)
        vf[c] = *(const bf16x8*)&Vt[(long)(w * 128 + c * 16 + l15) * 2048 +
                                    mb + mq * 32 + quad * 8];
      bf16x8 pa[2];
#pragma unroll
      for (int r = 0; r < 2; ++r)
        pa[r] = *(const bf16x8*)((const char*)Ps + w * 4096 + (r * 16 + l15) * 128 +
                                 ((mq * 64 + quad * 16) ^ sw4));
#pragma unroll
      for (int c = 0; c < 8; ++c)
#pragma unroll
        for (int r = 0; r < 2; ++r)
          accp[r][c] = __builtin_amdgcn_mfma_f32_16x16x32_bf16(pa[r], vf[c], accp[r][c], 0, 0, 0);
    }
  }
  // ---- store bf16 partial [n][h*128+d] ----
#pragma unroll
  for (int r = 0; r < 2; ++r)
#pragma unroll
    for (int c = 0; c < 8; ++c)
#pragma unroll
      for (int i = 0; i < 4; ++i)
        part[(long)(n0 + r * 16 + quad * 4 + i) * 1024 + w * 128 + c * 16 + l15] =
            f32_bf16(accp[r][c][i]);
}

// out = bf16(sum of 8 contiguous partials)
__global__ __launch_bounds__(256) void reduce8p_bf16(
    const u16* __restrict__ base, u16* __restrict__ out) {
  long i = (long)blockIdx.x * 256 + threadIdx.x;  // ushort4 idx, 524288 total
  const long stride = (long)BS * 1024 / 4;        // partial stride in ushort4
  float sx = 0.f, sy = 0.f, sz = 0.f, sw = 0.f;
#pragma unroll
  for (int k = 0; k < 8; ++k) {
    ushort4 a = ((const ushort4*)base)[i + k * stride];
    sx += bf2f(a.x); sy += bf2f(a.y); sz += bf2f(a.z); sw += bf2f(a.w);
  }
  ushort4 o;
  o.x = f32_bf16(sx); o.y = f32_bf16(sy); o.z = f32_bf16(sz); o.w = f32_bf16(sw);
  ((ushort4*)out)[i] = o;
}

// ---- residual + 4 bf16 partials + column-bias + layernorm; fp32 (+bf16) out ----
__global__ __launch_bounds__(256) void ln_residual_p4(
    const float* __restrict__ x,
    const u16* __restrict__ p0, const u16* __restrict__ p1,
    const u16* __restrict__ p2, const u16* __restrict__ p3,
    const float* __restrict__ colb, const float* __restrict__ g, const float* __restrict__ b,
    float* __restrict__ out32, u16* __restrict__ out16) {
  const int row = blockIdx.x, t = threadIdx.x;
  const long base = (long)row * EMB;
  float4 v = ((const float4*)(x + base))[t];
  ushort4 a0 = ((const ushort4*)(p0 + base))[t];
  ushort4 a1 = ((const ushort4*)(p1 + base))[t];
  ushort4 a2 = ((const ushort4*)(p2 + base))[t];
  ushort4 a3 = ((const ushort4*)(p3 + base))[t];
  float4 cb = ((const float4*)colb)[t];
  v.x += bf2f(a0.x) + bf2f(a1.x) + bf2f(a2.x) + bf2f(a3.x) + cb.x;
  v.y += bf2f(a0.y) + bf2f(a1.y) + bf2f(a2.y) + bf2f(a3.y) + cb.y;
  v.z += bf2f(a0.z) + bf2f(a1.z) + bf2f(a2.z) + bf2f(a3.z) + cb.z;
  v.w += bf2f(a0.w) + bf2f(a1.w) + bf2f(a2.w) + bf2f(a3.w) + cb.w;
  float s = v.x + v.y + v.z + v.w;
  float q = v.x * v.x + v.y * v.y + v.z * v.z + v.w * v.w;
#pragma unroll
  for (int off = 32; off > 0; off >>= 1) {
    s += __shfl_xor(s, off);
    q += __shfl_xor(q, off);
  }
  __shared__ float red[8];
  const int wv = t >> 6, lane = t & 63;
  if (lane == 0) { red[wv] = s; red[4 + wv] = q; }
  __syncthreads();
  s = red[0] + red[1] + red[2] + red[3];
  q = red[4] + red[5] + red[6] + red[7];
  const float mean = s * (1.f / EMB);
  const float var = q * (1.f / EMB) - mean * mean;
  const float rstd = rsqrtf(var + 1e-5f);
  float4 gg = ((const float4*)g)[t];
  float4 bb = ((const float4*)b)[t];
  float4 o;
  o.x = (v.x - mean) * rstd * gg.x + bb.x;
  o.y = (v.y - mean) * rstd * gg.y + bb.y;
  o.z = (v.z - mean) * rstd * gg.z + bb.z;
  o.w = (v.w - mean) * rstd * gg.w + bb.w;
  ((float4*)(out32 + base))[t] = o;
  if (out16) {
    ushort4 ho;
    ho.x = f32_bf16(o.x); ho.y = f32_bf16(o.y); ho.z = f32_bf16(o.z); ho.w = f32_bf16(o.w);
    ((ushort4*)(out16 + base))[t] = ho;
  }
}

extern "C" void kernel_launch(void* const* d_in, const int* in_sizes, int n_in,
                              void* d_out, int out_size, void* d_ws, size_t ws_size,
                              hipStream_t stream) {
  const float* x1 = (const float*)d_in[0];
  const float* x2 = (const float*)d_in[1];
  const float* Wq = (const float*)d_in[2];
  const float* bq = (const float*)d_in[3];
  const float* Wk = (const float*)d_in[4];
  const float* bk = (const float*)d_in[5];
  const float* Wv = (const float*)d_in[6];
  const float* bv = (const float*)d_in[7];
  const float* Wo = (const float*)d_in[8];
  const float* bo = (const float*)d_in[9];
  const float* W1 = (const float*)d_in[10];
  const float* b1 = (const float*)d_in[11];
  const float* W2 = (const float*)d_in[12];
  const float* b2 = (const float*)d_in[13];
  const float* g1 = (const float*)d_in[14];
  const float* be1 = (const float*)d_in[15];
  const float* g2 = (const float*)d_in[16];
  const float* be2 = (const float*)d_in[17];

  char* ws = (char*)d_ws;
  const size_t MB = 1ull << 20;
  // bf16 convert region (contiguous, 32 MB):
  u16* x1b = (u16*)(ws + 0 * MB);
  u16* x2b = (u16*)(ws + 4 * MB);
  u16* Wqb = (u16*)(ws + 8 * MB);
  u16* Wkb = (u16*)(ws + 10 * MB);
  u16* Wvb = (u16*)(ws + 12 * MB);
  u16* Wob = (u16*)(ws + 14 * MB);
  u16* W1b = (u16*)(ws + 16 * MB);
  u16* W2b = (u16*)(ws + 24 * MB);
  // attention buffers:
  u16* Qb  = (u16*)(ws + 32 * MB);
  u16* Kb  = (u16*)(ws + 36 * MB);
  u16* Vtb = (u16*)(ws + 40 * MB);   // 4 MB (transposed V: [h*128+d][m], ld 2048)
  u16* attnb = (u16*)(ws + 44 * MB); // 4 MB
  // fused-attn partials: 8 x 4 MB contiguous at 48..80 MB (h32/h16/ffn1b at
  // 64..80 are written only AFTER reduce8p consumed these -- safe aliasing)
  u16* aP = (u16*)(ws + 48 * MB);
  // post-attention region (reuses 48..64 AFTER reduce8p consumed aP):
  u16* woP[4] = {(u16*)(ws + 48 * MB), (u16*)(ws + 52 * MB),
                 (u16*)(ws + 56 * MB), (u16*)(ws + 60 * MB)};   // 16 MB
  float* h32  = (float*)(ws + 64 * MB);  // 8 MB
  u16*  h16   = (u16*)(ws + 72 * MB);    // 4 MB
  u16*  ffn1b = (u16*)(ws + 76 * MB);    // 16 MB
  u16* f2P[4] = {(u16*)(ws + 92 * MB), (u16*)(ws + 96 * MB),
                 (u16*)(ws + 100 * MB), (u16*)(ws + 104 * MB)}; // 16 MB -> 108 peak

  // 1. all fp32->bf16 conversions
  CvtArgs ca;
  ca.src[0] = x1; ca.src[1] = x2; ca.src[2] = Wq; ca.src[3] = Wk;
  ca.src[4] = Wv; ca.src[5] = Wo; ca.src[6] = W1; ca.src[7] = W2;
  cvt_all<<<16384, 256, 0, stream>>>(ca, (u16*)ws);

  // 2. Q/K/V projections (one launch, 384 blocks)
  qkv_kernel<<<dim3(8, 16, 3), 256, 0, stream>>>(x1b, x2b, Wqb, Wkb, Wvb, bq, bk, bv, Qb, Kb, Vtb);

  // 3. fused QK^T + softmax(heads) + PV -> 8 bf16 partials (512 blocks, 2/CU)
  attn_fused<<<dim3(64, 8), 512, 0, stream>>>(Qb, Kb, Vtb, aP);

  // 4. attnb = sum of 8 partials
  reduce8p_bf16<<<2048, 256, 0, stream>>>(aP, attnb);

  // 5. Wo GEMM split-K x4 (512 blocks), bf16 partials (bias folded into LN)
  gemm_bt_k<<<dim3(8, 16, 4), 256, 0, stream>>>(attnb, Wob, woP[0], nullptr,
                                                256, 1024, 1024, 1024,
                                                256, 256, (long)BS * 1024, 1, 0);

  // 6. h = LN(x1 + sum(woP) + bo)
  ln_residual_p4<<<2048, 256, 0, stream>>>(x1, woP[0], woP[1], woP[2], woP[3],
                                           bo, g1, be1, h32, h16);

  // 7. FFN1 (+bias+relu), 512 blocks
  gemm_bt_k<<<dim3(32, 16, 1), 256, 0, stream>>>(h16, W1b, ffn1b, b1,
                                                 1024, 1024, 1024, 4096,
                                                 0, 0, 0, 1, 1);

  // 8. FFN2 split-K x4 (512 blocks), bf16 partials (bias folded into LN)
  gemm_bt_k<<<dim3(8, 16, 4), 256, 0, stream>>>(ffn1b, W2b, f2P[0], nullptr,
                                                1024, 4096, 4096, 1024,
                                                1024, 1024, (long)BS * 1024, 1, 0);

  // 9. out = LN(h + sum(f2P) + b2)
  ln_residual_p4<<<2048, 256, 0, stream>>>(h32, f2P[0], f2P[1], f2P[2], f2P[3],
                                           b2, g2, be2, (float*)d_out, nullptr);
}

// Round 9
// 331.086 us; speedup vs baseline: 1.3503x; 1.0806x over previous
//
#include <hip/hip_runtime.h>

#define BS 2048
#define EMB 1024
#define NHEAD 8
#define HDIM 128

typedef unsigned short u16;
typedef __attribute__((ext_vector_type(8))) short bf16x8;
typedef __attribute__((ext_vector_type(4))) float f32x4;

__device__ __forceinline__ u16 f32_bf16(float f) {
  unsigned u = __float_as_uint(f);
  u += 0x7fffu + ((u >> 16) & 1u);
  return (u16)(u >> 16);
}
__device__ __forceinline__ float bf2f(u16 x) {
  return __uint_as_float((unsigned)x << 16);
}

__device__ __forceinline__ void gld_lds16(const void* g, void* l) {
  __builtin_amdgcn_global_load_lds(
      (const __attribute__((address_space(1))) void*)g,
      (__attribute__((address_space(3))) void*)l, 16, 0, 0);
}

// ---------------- fp32 -> bf16: ALL weights/activations in ONE kernel ----------
// segs of 256K v4 (1M elems): [0,2)=x1 [2,4)=x2 [4]=Wq [5]=Wk [6]=Wv [7]=Wo
// [8,12)=W1 [12,16)=W2
struct CvtArgs { const float* src[8]; };
__global__ __launch_bounds__(256) void cvt_all(CvtArgs a, u16* __restrict__ dst) {
  long i = (long)blockIdx.x * 256 + threadIdx.x;  // v4 index
  int seg = (int)(i >> 18);
  const float* src; long b;
  if (seg < 2)       { src = a.src[0]; b = 0; }
  else if (seg < 4)  { src = a.src[1]; b = 2L << 18; }
  else if (seg == 4) { src = a.src[2]; b = 4L << 18; }
  else if (seg == 5) { src = a.src[3]; b = 5L << 18; }
  else if (seg == 6) { src = a.src[4]; b = 6L << 18; }
  else if (seg == 7) { src = a.src[5]; b = 7L << 18; }
  else if (seg < 12) { src = a.src[6]; b = 8L << 18; }
  else               { src = a.src[7]; b = 12L << 18; }
  float4 v = ((const float4*)src)[i - b];
  ushort4 o;
  o.x = f32_bf16(v.x); o.y = f32_bf16(v.y); o.z = f32_bf16(v.z); o.w = f32_bf16(v.w);
  ((ushort4*)dst)[i] = o;
}

// ---------------- GEMM core: C = A @ B^T (+bias), 128x128 tile, BK=32 ----------
// mode: 0 = fp32 out, 1 = bf16 out, 2 = bf16 transposed store (Ct[n][m])
__device__ __forceinline__ void gemm_core(
    const u16* __restrict__ A, const u16* __restrict__ B, void* __restrict__ Cp,
    const float* __restrict__ bias, int K, int lda, int ldb, int ldc,
    long cbase, int mode, int relu, int m0, int n0) {
  __shared__ __align__(16) u16 As[128 * 32];
  __shared__ __align__(16) u16 Bs[128 * 32];
  const int t = threadIdx.x;
  const int lane = t & 63, l15 = lane & 15, quad = lane >> 4;
  const int wv = t >> 6, wr = wv & 1, wc = wv >> 1;
  const int wbase = t & ~63;

  f32x4 acc[4][4];
#pragma unroll
  for (int r = 0; r < 4; ++r)
#pragma unroll
    for (int c = 0; c < 4; ++c) acc[r][c] = (f32x4){0.f, 0.f, 0.f, 0.f};

  for (int k0 = 0; k0 < K; k0 += 32) {
#pragma unroll
    for (int i = 0; i < 2; ++i) {
      int s = i * 256 + t;
      gld_lds16(A + (long)(m0 + (s >> 2)) * lda + k0 + (s & 3) * 8,
                As + (i * 256 + wbase) * 8);
    }
#pragma unroll
    for (int i = 0; i < 2; ++i) {
      int s = i * 256 + t;
      gld_lds16(B + (long)(n0 + (s >> 2)) * ldb + k0 + (s & 3) * 8,
                Bs + (i * 256 + wbase) * 8);
    }
    __syncthreads();
    bf16x8 fa[4], fb[4];
#pragma unroll
    for (int r = 0; r < 4; ++r)
      fa[r] = *(const bf16x8*)&As[(wr * 64 + r * 16 + l15) * 32 + quad * 8];
#pragma unroll
    for (int c = 0; c < 4; ++c)
      fb[c] = *(const bf16x8*)&Bs[(wc * 64 + c * 16 + l15) * 32 + quad * 8];
#pragma unroll
    for (int r = 0; r < 4; ++r)
#pragma unroll
      for (int c = 0; c < 4; ++c)
        acc[r][c] = __builtin_amdgcn_mfma_f32_16x16x32_bf16(fa[r], fb[c], acc[r][c], 0, 0, 0);
    __syncthreads();
  }

#pragma unroll
  for (int r = 0; r < 4; ++r)
#pragma unroll
    for (int c = 0; c < 4; ++c) {
      const int m = m0 + wr * 64 + r * 16 + quad * 4;
      const int n = n0 + wc * 64 + c * 16 + l15;
      const float bv = bias ? bias[n] : 0.f;
      f32x4 v = acc[r][c];
      if (mode == 2) {
        ushort4 o;
        o.x = f32_bf16(v[0] + bv);
        o.y = f32_bf16(v[1] + bv);
        o.z = f32_bf16(v[2] + bv);
        o.w = f32_bf16(v[3] + bv);
        *(ushort4*)((u16*)Cp + cbase + (long)n * ldc + m) = o;
      } else {
#pragma unroll
        for (int i = 0; i < 4; ++i) {
          float x = v[i] + bv;
          if (relu) x = fmaxf(x, 0.f);
          if (mode == 0)
            ((float*)Cp)[cbase + (long)(m + i) * ldc + n] = x;
          else
            ((u16*)Cp)[cbase + (long)(m + i) * ldc + n] = f32_bf16(x);
        }
      }
    }
}

// generic z-batched GEMM (linear z offsets in elements)
__global__ __launch_bounds__(256) void gemm_bt_k(
    const u16* __restrict__ A, const u16* __restrict__ B, void* __restrict__ C,
    const float* __restrict__ bias, int K, int lda, int ldb, int ldc,
    long aOffZ, long bOffZ, long cOffZ, int mode, int relu) {
  gemm_core(A + (long)blockIdx.z * aOffZ, B + (long)blockIdx.z * bOffZ, C, bias,
            K, lda, ldb, ldc, (long)blockIdx.z * cOffZ, mode, relu,
            blockIdx.y * 128, blockIdx.x * 128);
}

// Q/K/V projections in one launch: z=0 Q(x1), z=1 K(x2), z=2 V(x2, transposed out)
__global__ __launch_bounds__(256) void qkv_kernel(
    const u16* __restrict__ x1b, const u16* __restrict__ x2b,
    const u16* __restrict__ Wqb, const u16* __restrict__ Wkb, const u16* __restrict__ Wvb,
    const float* __restrict__ bq, const float* __restrict__ bk, const float* __restrict__ bv,
    u16* __restrict__ Qb, u16* __restrict__ Kb, u16* __restrict__ Vt) {
  const int z = blockIdx.z;
  const u16* A = (z == 0) ? x1b : x2b;
  const u16* B = (z == 0) ? Wqb : (z == 1) ? Wkb : Wvb;
  void* C = (z == 0) ? (void*)Qb : (z == 1) ? (void*)Kb : (void*)Vt;
  const float* bias = (z == 0) ? bq : (z == 1) ? bk : bv;
  const int mode = (z == 2) ? 2 : 1;
  const int ldc = (z == 2) ? 2048 : 1024;
  gemm_core(A, B, C, bias, 1024, 1024, 1024, ldc, 0, mode, 0,
            blockIdx.y * 128, blockIdx.x * 128);
}

// ---------------- fused attention: QK^T + softmax(heads) + PV -----------------
// Exact R4 structure (74 us verified) + XCD-aware bijective block remap:
// linear wgid = x + 64*y dispatches round-robin to XCDs (g = wgid&7).
// Remap: m-split my = g>>1, n-block nx = (g&1)*32 + (wgid>>3).
// -> each XCD owns ONE m-split and one n-half: K-slab 1MB + V-window 1MB +
// Q-slice 2MB = 4MB = exactly its L2 (vs 12MB scattered before).
// 512 threads, 8 waves, LDS 144 KB, 1 block/CU.
// 2-phase pipelined staging: per (it, h) step one combined 40 KB slab
//   K[128m][128k_h] + Q[32n][128k_h] into a double buffer via async
//   global_load_lds, XOR-swizzled through the pre-swizzled global source.
//   Per step: sync (drains stage issued LAST step, overlapped with compute)
//   -> issue stage(next, buf^1) -> compute(cur). One barrier/step.
// accs[8][2] per lane (all heads) -> per-lane softmax over heads.
// P -> LDS [h][32n][128m] bf16 XOR-swizzled; PV: wave w owns head w, V direct
// global batched vf[8] per mq. Partials reduced by reduce4p_bf16.
__global__ __launch_bounds__(512, 2) void attn_fused(
    const u16* __restrict__ Q, const u16* __restrict__ Km, const u16* __restrict__ Vt,
    u16* __restrict__ p0, u16* __restrict__ p1, u16* __restrict__ p2, u16* __restrict__ p3) {
  __shared__ __align__(16) u16 KQ[2 * 20480];     // 2 x (128+32) rows x 128 = 80 KB
  __shared__ __align__(16) u16 Ps[8 * 32 * 128];  // 64 KB, [h][n][m] swizzled
  const int t = threadIdx.x;
  const int lane = t & 63, l15 = lane & 15, quad = lane >> 4;
  const int w = t >> 6;
  // XCD-aware bijective remap (256 blocks: g=xcd, u=index-on-xcd)
  const int lin = blockIdx.x + (int)gridDim.x * blockIdx.y;
  const int g = lin & 7, u = lin >> 3;
  const int my = g >> 1;                 // m-split 0..3
  const int nx = (g & 1) * 32 + u;       // n-block 0..63
  const int n0 = nx * 32;
  const int mz = my * 512;
  u16* part = (my == 0) ? p0 : (my == 1) ? p1 : (my == 2) ? p2 : p3;

  // stage step snum (= it*8 + h) into buffer bsel.
  // LDS granule G (16B): row r = G>>4 (0..127 = K row m, 128..159 = Q row n),
  // in-row granule g2 = G&15, data = row[(g2 ^ (r&7))*8 ..] (pre-swizzled src).
  auto stage = [&](int snum, int bsel) {
    const int sh = (snum & 7) * 128;
    const int smb = mz + (snum >> 3) * 128;
#pragma unroll
    for (int i = 0; i < 5; ++i) {
      int G = i * 512 + t;
      int r = G >> 4, g2 = G & 15;
      const u16* src;
      if (i < 4) src = Km + (long)(smb + r) * 1024 + sh + ((g2 ^ (r & 7)) << 3);
      else       src = Q + (long)(n0 + r - 128) * 1024 + sh + ((g2 ^ (r & 7)) << 3);
      gld_lds16(src, KQ + bsel * 20480 + G * 8);
    }
  };

  f32x4 accp[2][8];
#pragma unroll
  for (int r = 0; r < 2; ++r)
#pragma unroll
    for (int c = 0; c < 8; ++c) accp[r][c] = (f32x4){0.f, 0.f, 0.f, 0.f};

  int b = 0;
  stage(0, 0);

  for (int it = 0; it < 4; ++it) {
    const int mb = mz + it * 128;
    f32x4 accs[8][2];
#pragma unroll
    for (int h = 0; h < 8; ++h)
#pragma unroll
      for (int c = 0; c < 2; ++c) accs[h][c] = (f32x4){0.f, 0.f, 0.f, 0.f};

#pragma unroll
    for (int h = 0; h < 8; ++h) {
      __syncthreads();  // drains stage(cur) (vmcnt0+lgkm0), closes prev readers
      int ns = it * 8 + h + 1;
      if (ns < 32) stage(ns, b ^ 1);  // overlaps with compute below
      const u16* kb = KQ + b * 20480;
      const u16* qb = kb + 128 * 128;
      const int m = w * 16 + l15;
#pragma unroll
      for (int kk = 0; kk < 4; ++kk) {
        int ko = (kk * 32 + quad * 8) ^ ((l15 & 7) << 3);
        bf16x8 fa = *(const bf16x8*)&kb[m * 128 + ko];
        bf16x8 fb0 = *(const bf16x8*)&qb[l15 * 128 + ko];
        bf16x8 fb1 = *(const bf16x8*)&qb[(16 + l15) * 128 + ko];
        accs[h][0] = __builtin_amdgcn_mfma_f32_16x16x32_bf16(fa, fb0, accs[h][0], 0, 0, 0);
        accs[h][1] = __builtin_amdgcn_mfma_f32_16x16x32_bf16(fa, fb1, accs[h][1], 0, 0, 0);
      }
      b ^= 1;
    }

    // ---- softmax over heads, per-lane; i indexes m (rows of S^T) ----
    const float scale = 0.08838834764831845f;  // 1/sqrt(128)
#pragma unroll
    for (int c = 0; c < 2; ++c)
#pragma unroll
      for (int i = 0; i < 4; ++i) {
        float mx = accs[0][c][i];
#pragma unroll
        for (int h = 1; h < 8; ++h) mx = fmaxf(mx, accs[h][c][i]);
        float sum = 0.f;
#pragma unroll
        for (int h = 0; h < 8; ++h) {
          float e = __expf((accs[h][c][i] - mx) * scale);
          accs[h][c][i] = e;
          sum += e;
        }
        float inv = 1.f / sum;
#pragma unroll
        for (int h = 0; h < 8; ++h) accs[h][c][i] *= inv;
      }
    // ---- P -> LDS, m-packed ushort4, swizzled ----
#pragma unroll
    for (int h = 0; h < 8; ++h)
#pragma unroll
      for (int c = 0; c < 2; ++c) {
        int n = c * 16 + l15;
        ushort4 o;
        o.x = f32_bf16(accs[h][c][0]);
        o.y = f32_bf16(accs[h][c][1]);
        o.z = f32_bf16(accs[h][c][2]);
        o.w = f32_bf16(accs[h][c][3]);
        *(ushort4*)((char*)Ps + h * 8192 + n * 256 + ((w * 32 + quad * 8) ^ ((n & 7) << 4))) = o;
      }
    __syncthreads();  // Ps ready (PV reads of prev it all closed by h-loop barriers)
    // ---- PV: head w; C[n32][d128] += P[n][m128] * Vt[d][m128]^T ----
    // (overlaps the already-issued stage of next it's h=0 slab)
#pragma unroll
    for (int mq = 0; mq < 4; ++mq) {
      bf16x8 vf[8];
#pragma unroll
      for (int c = 0; c < 8; ++c)
        vf[c] = *(const bf16x8*)&Vt[(long)(w * 128 + c * 16 + l15) * 2048 +
                                    mb + mq * 32 + quad * 8];
      bf16x8 pa[2];
#pragma unroll
      for (int r = 0; r < 2; ++r) {
        int n = r * 16 + l15;
        pa[r] = *(const bf16x8*)((const char*)Ps + w * 8192 + n * 256 +
                                 ((mq * 64 + quad * 16) ^ ((n & 7) << 4)));
      }
#pragma unroll
      for (int c = 0; c < 8; ++c)
#pragma unroll
        for (int r = 0; r < 2; ++r)
          accp[r][c] = __builtin_amdgcn_mfma_f32_16x16x32_bf16(pa[r], vf[c], accp[r][c], 0, 0, 0);
    }
  }
  // ---- store bf16 partial [n][h*128+d] ----
#pragma unroll
  for (int r = 0; r < 2; ++r)
#pragma unroll
    for (int c = 0; c < 8; ++c)
#pragma unroll
      for (int i = 0; i < 4; ++i)
        part[(long)(n0 + r * 16 + quad * 4 + i) * 1024 + w * 128 + c * 16 + l15] =
            f32_bf16(accp[r][c][i]);
}

// out = bf16(p0+p1+p2+p3)
__global__ __launch_bounds__(256) void reduce4p_bf16(
    const u16* __restrict__ p0, const u16* __restrict__ p1,
    const u16* __restrict__ p2, const u16* __restrict__ p3, u16* __restrict__ out) {
  long i = (long)blockIdx.x * 256 + threadIdx.x;  // ushort4 idx, 524288 total
  ushort4 a = ((const ushort4*)p0)[i];
  ushort4 b = ((const ushort4*)p1)[i];
  ushort4 c = ((const ushort4*)p2)[i];
  ushort4 d = ((const ushort4*)p3)[i];
  ushort4 o;
  o.x = f32_bf16(bf2f(a.x) + bf2f(b.x) + bf2f(c.x) + bf2f(d.x));
  o.y = f32_bf16(bf2f(a.y) + bf2f(b.y) + bf2f(c.y) + bf2f(d.y));
  o.z = f32_bf16(bf2f(a.z) + bf2f(b.z) + bf2f(c.z) + bf2f(d.z));
  o.w = f32_bf16(bf2f(a.w) + bf2f(b.w) + bf2f(c.w) + bf2f(d.w));
  ((ushort4*)out)[i] = o;
}

// ---- residual + 4 bf16 partials + column-bias + layernorm; fp32 (+bf16) out ----
__global__ __launch_bounds__(256) void ln_residual_p4(
    const float* __restrict__ x,
    const u16* __restrict__ p0, const u16* __restrict__ p1,
    const u16* __restrict__ p2, const u16* __restrict__ p3,
    const float* __restrict__ colb, const float* __restrict__ g, const float* __restrict__ b,
    float* __restrict__ out32, u16* __restrict__ out16) {
  const int row = blockIdx.x, t = threadIdx.x;
  const long base = (long)row * EMB;
  float4 v = ((const float4*)(x + base))[t];
  ushort4 a0 = ((const ushort4*)(p0 + base))[t];
  ushort4 a1 = ((const ushort4*)(p1 + base))[t];
  ushort4 a2 = ((const ushort4*)(p2 + base))[t];
  ushort4 a3 = ((const ushort4*)(p3 + base))[t];
  float4 cb = ((const float4*)colb)[t];
  v.x += bf2f(a0.x) + bf2f(a1.x) + bf2f(a2.x) + bf2f(a3.x) + cb.x;
  v.y += bf2f(a0.y) + bf2f(a1.y) + bf2f(a2.y) + bf2f(a3.y) + cb.y;
  v.z += bf2f(a0.z) + bf2f(a1.z) + bf2f(a2.z) + bf2f(a3.z) + cb.z;
  v.w += bf2f(a0.w) + bf2f(a1.w) + bf2f(a2.w) + bf2f(a3.w) + cb.w;
  float s = v.x + v.y + v.z + v.w;
  float q = v.x * v.x + v.y * v.y + v.z * v.z + v.w * v.w;
#pragma unroll
  for (int off = 32; off > 0; off >>= 1) {
    s += __shfl_xor(s, off);
    q += __shfl_xor(q, off);
  }
  __shared__ float red[8];
  const int wv = t >> 6, lane = t & 63;
  if (lane == 0) { red[wv] = s; red[4 + wv] = q; }
  __syncthreads();
  s = red[0] + red[1] + red[2] + red[3];
  q = red[4] + red[5] + red[6] + red[7];
  const float mean = s * (1.f / EMB);
  const float var = q * (1.f / EMB) - mean * mean;
  const float rstd = rsqrtf(var + 1e-5f);
  float4 gg = ((const float4*)g)[t];
  float4 bb = ((const float4*)b)[t];
  float4 o;
  o.x = (v.x - mean) * rstd * gg.x + bb.x;
  o.y = (v.y - mean) * rstd * gg.y + bb.y;
  o.z = (v.z - mean) * rstd * gg.z + bb.z;
  o.w = (v.w - mean) * rstd * gg.w + bb.w;
  ((float4*)(out32 + base))[t] = o;
  if (out16) {
    ushort4 ho;
    ho.x = f32_bf16(o.x); ho.y = f32_bf16(o.y); ho.z = f32_bf16(o.z); ho.w = f32_bf16(o.w);
    ((ushort4*)(out16 + base))[t] = ho;
  }
}

extern "C" void kernel_launch(void* const* d_in, const int* in_sizes, int n_in,
                              void* d_out, int out_size, void* d_ws, size_t ws_size,
                              hipStream_t stream) {
  const float* x1 = (const float*)d_in[0];
  const float* x2 = (const float*)d_in[1];
  const float* Wq = (const float*)d_in[2];
  const float* bq = (const float*)d_in[3];
  const float* Wk = (const float*)d_in[4];
  const float* bk = (const float*)d_in[5];
  const float* Wv = (const float*)d_in[6];
  const float* bv = (const float*)d_in[7];
  const float* Wo = (const float*)d_in[8];
  const float* bo = (const float*)d_in[9];
  const float* W1 = (const float*)d_in[10];
  const float* b1 = (const float*)d_in[11];
  const float* W2 = (const float*)d_in[12];
  const float* b2 = (const float*)d_in[13];
  const float* g1 = (const float*)d_in[14];
  const float* be1 = (const float*)d_in[15];
  const float* g2 = (const float*)d_in[16];
  const float* be2 = (const float*)d_in[17];

  char* ws = (char*)d_ws;
  const size_t MB = 1ull << 20;
  // bf16 convert region (contiguous, 32 MB):
  u16* x1b = (u16*)(ws + 0 * MB);
  u16* x2b = (u16*)(ws + 4 * MB);
  u16* Wqb = (u16*)(ws + 8 * MB);
  u16* Wkb = (u16*)(ws + 10 * MB);
  u16* Wvb = (u16*)(ws + 12 * MB);
  u16* Wob = (u16*)(ws + 14 * MB);
  u16* W1b = (u16*)(ws + 16 * MB);
  u16* W2b = (u16*)(ws + 24 * MB);
  // attention buffers:
  u16* Qb  = (u16*)(ws + 32 * MB);
  u16* Kb  = (u16*)(ws + 36 * MB);
  u16* Vtb = (u16*)(ws + 40 * MB);   // 4 MB (transposed V: [h*128+d][m], ld 2048)
  u16* attnb = (u16*)(ws + 44 * MB); // 4 MB
  // fused-attn partials (16 MB, in the old P region):
  u16* aP[4] = {(u16*)(ws + 48 * MB), (u16*)(ws + 52 * MB),
                (u16*)(ws + 56 * MB), (u16*)(ws + 60 * MB)};
  // post-attention region (reuses same region AFTER reduce4p consumed aP):
  u16* woP[4] = {(u16*)(ws + 48 * MB), (u16*)(ws + 52 * MB),
                 (u16*)(ws + 56 * MB), (u16*)(ws + 60 * MB)};   // 16 MB
  float* h32  = (float*)(ws + 64 * MB);  // 8 MB
  u16*  h16   = (u16*)(ws + 72 * MB);    // 4 MB
  u16*  ffn1b = (u16*)(ws + 76 * MB);    // 16 MB
  u16* f2P[4] = {(u16*)(ws + 92 * MB), (u16*)(ws + 96 * MB),
                 (u16*)(ws + 100 * MB), (u16*)(ws + 104 * MB)}; // 16 MB -> 108 peak

  // 1. all fp32->bf16 conversions
  CvtArgs ca;
  ca.src[0] = x1; ca.src[1] = x2; ca.src[2] = Wq; ca.src[3] = Wk;
  ca.src[4] = Wv; ca.src[5] = Wo; ca.src[6] = W1; ca.src[7] = W2;
  cvt_all<<<16384, 256, 0, stream>>>(ca, (u16*)ws);

  // 2. Q/K/V projections (one launch, 384 blocks)
  qkv_kernel<<<dim3(8, 16, 3), 256, 0, stream>>>(x1b, x2b, Wqb, Wkb, Wvb, bq, bk, bv, Qb, Kb, Vtb);

  // 3. fused QK^T + softmax(heads) + PV -> 4 bf16 partials (256 blocks, 1/CU)
  attn_fused<<<dim3(64, 4), 512, 0, stream>>>(Qb, Kb, Vtb, aP[0], aP[1], aP[2], aP[3]);

  // 4. attnb = sum of 4 partials
  reduce4p_bf16<<<2048, 256, 0, stream>>>(aP[0], aP[1], aP[2], aP[3], attnb);

  // 5. Wo GEMM split-K x4 (512 blocks), bf16 partials (bias folded into LN)
  gemm_bt_k<<<dim3(8, 16, 4), 256, 0, stream>>>(attnb, Wob, woP[0], nullptr,
                                                256, 1024, 1024, 1024,
                                                256, 256, (long)BS * 1024, 1, 0);

  // 6. h = LN(x1 + sum(woP) + bo)
  ln_residual_p4<<<2048, 256, 0, stream>>>(x1, woP[0], woP[1], woP[2], woP[3],
                                           bo, g1, be1, h32, h16);

  // 7. FFN1 (+bias+relu), 512 blocks
  gemm_bt_k<<<dim3(32, 16, 1), 256, 0, stream>>>(h16, W1b, ffn1b, b1,
                                                 1024, 1024, 1024, 4096,
                                                 0, 0, 0, 1, 1);

  // 8. FFN2 split-K x4 (512 blocks), bf16 partials (bias folded into LN)
  gemm_bt_k<<<dim3(8, 16, 4), 256, 0, stream>>>(ffn1b, W2b, f2P[0], nullptr,
                                                1024, 4096, 4096, 1024,
                                                1024, 1024, (long)BS * 1024, 1, 0);

  // 9. out = LN(h + sum(f2P) + b2)
  ln_residual_p4<<<2048, 256, 0, stream>>>(h32, f2P[0], f2P[1], f2P[2], f2P[3],
                                           b2, g2, be2, (float*)d_out, nullptr);
}